// Round 3
// baseline (580.690 us; speedup 1.0000x reference)
//
#include <hip/hip_runtime.h>

typedef __attribute__((ext_vector_type(8))) short short8;
typedef __attribute__((ext_vector_type(4))) float f32x4;

#define B_ 4
#define S_ 2048
#define D_ 512
#define H_ 8
#define HD_ 64

__device__ __forceinline__ unsigned short f2bf(float f) {
    unsigned int u = __float_as_uint(f);
    u += 0x7fffu + ((u >> 16) & 1u);
    return (unsigned short)(u >> 16);
}
__device__ __forceinline__ float bf2f(unsigned short h) {
    return __uint_as_float(((unsigned int)h) << 16);
}
__device__ __forceinline__ short8 ld8(const unsigned short* p) {
    return *reinterpret_cast<const short8*>(p);
}

// Dual-dtype 8-element A-row load -> bf16 fragment
__device__ __forceinline__ short8 ldA_dual(const void* X, size_t eoff, int isf32) {
    if (isf32) {
        const float* f = (const float*)X + eoff;
        f32x4 u = *(const f32x4*)f;
        f32x4 v = *(const f32x4*)(f + 4);
        short8 r;
        r[0] = (short)f2bf(u[0]); r[1] = (short)f2bf(u[1]);
        r[2] = (short)f2bf(u[2]); r[3] = (short)f2bf(u[3]);
        r[4] = (short)f2bf(v[0]); r[5] = (short)f2bf(v[1]);
        r[6] = (short)f2bf(v[2]); r[7] = (short)f2bf(v[3]);
        return r;
    }
    return ld8((const unsigned short*)X + eoff);
}

// ---------------- dtype probe: 1 => inputs are f32, 0 => bf16
__global__ void detect_dtype(const unsigned short* __restrict__ q, int* __restrict__ flag) {
    __shared__ int cnt[256];
    int t = threadIdx.x;
    float x = bf2f(q[t]);
    float a = fabsf(x);
    cnt[t] = (a > 1e-5f && a < 1e3f) ? 1 : 0;
    __syncthreads();
    if (t == 0) {
        int s = 0;
        for (int i = 0; i < 256; i++) s += cnt[i];
        *flag = (s < 205) ? 1 : 0;   // bf16 data scores ~256; f32-as-bf16 scores ~140
    }
}

// ---------------- weight transpose: WT[n][k] = W[k][n], 512x512, z = which matrix
__global__ __launch_bounds__(256) void transpose512(
    const void* __restrict__ W0, const void* __restrict__ W1,
    const void* __restrict__ W2, const void* __restrict__ W3,
    unsigned short* __restrict__ outbase, const int* __restrict__ flagp)
{
    __shared__ unsigned short t[64][66];
    int fl = *flagp;
    const void* W = (blockIdx.z == 0) ? W0 : (blockIdx.z == 1) ? W1
                    : (blockIdx.z == 2) ? W2 : W3;
    unsigned short* o = outbase + (size_t)blockIdx.z * 262144;
    int k0 = blockIdx.x * 64, n0 = blockIdx.y * 64;
    int tx = threadIdx.x, ty = threadIdx.y;
#pragma unroll
    for (int r = 0; r < 16; r++) {
        int row = ty * 16 + r;
        size_t idx = (size_t)(k0 + row) * D_ + n0 + tx;
        float v = fl ? ((const float*)W)[idx] : bf2f(((const unsigned short*)W)[idx]);
        t[row][tx] = f2bf(v);
    }
    __syncthreads();
#pragma unroll
    for (int r = 0; r < 16; r++) {
        int row = ty * 16 + r;
        o[(size_t)(n0 + row) * D_ + k0 + tx] = t[tx][row];
    }
}

// ---------------- GEMM: C[8192,512] = X[8192,512] @ W (via WT[n][k]) + bias
// mode 0/1: scatter bf16 into [B,H,S,hd]; mode 2: V transposed bf16 into [B,H,hd,S];
// mode 3: row-major FLOAT32 out (d_out holds reference-output dtype = f32)
__global__ __launch_bounds__(256) void gemm512(
    const void* __restrict__ X, const unsigned short* __restrict__ WT,
    const void* __restrict__ bias, void* __restrict__ out, int mode,
    int aflagmask, const int* __restrict__ flagp)
{
    int fl = *flagp;
    int af = aflagmask & fl;
    int m0 = blockIdx.x * 64, n0 = blockIdx.y * 64;
    int tid = threadIdx.x;
    int w = tid >> 6, lane = tid & 63, lm = lane & 15, quad = lane >> 4;
    int mbase = m0 + w * 16;

    f32x4 acc[4];
#pragma unroll
    for (int nt = 0; nt < 4; nt++) acc[nt] = (f32x4){0.f, 0.f, 0.f, 0.f};

    size_t abase = (size_t)(mbase + lm) * D_ + quad * 8;
    for (int k0 = 0; k0 < D_; k0 += 32) {
        short8 a = ldA_dual(X, abase + k0, af);
#pragma unroll
        for (int nt = 0; nt < 4; nt++) {
            short8 b = ld8(WT + (size_t)(n0 + nt * 16 + lm) * D_ + k0 + quad * 8);
            acc[nt] = __builtin_amdgcn_mfma_f32_16x16x32_bf16(a, b, acc[nt], 0, 0, 0);
        }
    }

#pragma unroll
    for (int nt = 0; nt < 4; nt++) {
        int n = n0 + nt * 16 + lm;
        float bv = fl ? ((const float*)bias)[n] : bf2f(((const unsigned short*)bias)[n]);
#pragma unroll
        for (int r = 0; r < 4; r++) {
            int m = mbase + quad * 4 + r;
            float fv = acc[nt][r] + bv;
            if (mode == 3) {
                ((float*)out)[(size_t)m * D_ + n] = fv;          // f32 final output
            } else {
                unsigned short hv = f2bf(fv);
                int b = m >> 11, s = m & 2047;
                int hh = n >> 6, d = n & 63;
                if (mode == 2)
                    ((unsigned short*)out)[((size_t)(b * H_ + hh) * HD_ + d) * S_ + s] = hv;  // V^T
                else
                    ((unsigned short*)out)[((size_t)(b * H_ + hh) * S_ + s) * HD_ + d] = hv;  // Q, K
            }
        }
    }
}

// ---------------- flash attention (causal). Q,K: [B*H, S, hd]; VT: [B*H, hd, S]
// out ATT: [B, S, H*hd] row-major (merged heads)
__global__ __launch_bounds__(256) void attn_kernel(
    const unsigned short* __restrict__ Q, const unsigned short* __restrict__ K,
    const unsigned short* __restrict__ VT, unsigned short* __restrict__ ATT)
{
    __shared__ __align__(16) unsigned short Plds[4][16][72];
    int qt = blockIdx.x, bh = blockIdx.y;
    int tid = threadIdx.x;
    int w = tid >> 6, lane = tid & 63, lm = lane & 15, quad = lane >> 4;
    int q0 = qt * 64 + w * 16;   // first q-row of this wave's stripe

    const unsigned short* Qb = Q + (size_t)bh * S_ * HD_;
    const unsigned short* Kb = K + (size_t)bh * S_ * HD_;
    const unsigned short* Vb = VT + (size_t)bh * S_ * HD_;

    short8 aq0 = ld8(Qb + (size_t)(q0 + lm) * HD_ + quad * 8);
    short8 aq1 = ld8(Qb + (size_t)(q0 + lm) * HD_ + 32 + quad * 8);

    f32x4 o[4];
#pragma unroll
    for (int nt = 0; nt < 4; nt++) o[nt] = (f32x4){0.f, 0.f, 0.f, 0.f};
    float mrow[4], lrow[4];
#pragma unroll
    for (int r = 0; r < 4; r++) { mrow[r] = -INFINITY; lrow[r] = 0.f; }

    for (int kt = 0; kt <= qt; kt++) {
        f32x4 sc[4];
#pragma unroll
        for (int nt = 0; nt < 4; nt++) {
            const unsigned short* kr = Kb + (size_t)(kt * 64 + nt * 16 + lm) * HD_ + quad * 8;
            short8 b0 = ld8(kr);
            short8 b1 = ld8(kr + 32);
            f32x4 z = (f32x4){0.f, 0.f, 0.f, 0.f};
            z = __builtin_amdgcn_mfma_f32_16x16x32_bf16(aq0, b0, z, 0, 0, 0);
            z = __builtin_amdgcn_mfma_f32_16x16x32_bf16(aq1, b1, z, 0, 0, 0);
            sc[nt] = z;
        }
        bool diag = (kt == qt);
#pragma unroll
        for (int nt = 0; nt < 4; nt++) {
#pragma unroll
            for (int r = 0; r < 4; r++) {
                float v = sc[nt][r] * 0.125f;
                if (diag) {
                    int key = kt * 64 + nt * 16 + lm;
                    int q = q0 + quad * 4 + r;
                    if (key > q) v = -INFINITY;
                }
                sc[nt][r] = v;
            }
        }
        float alpha[4];
#pragma unroll
        for (int r = 0; r < 4; r++) {
            float vm = fmaxf(fmaxf(sc[0][r], sc[1][r]), fmaxf(sc[2][r], sc[3][r]));
            vm = fmaxf(vm, __shfl_xor(vm, 1));
            vm = fmaxf(vm, __shfl_xor(vm, 2));
            vm = fmaxf(vm, __shfl_xor(vm, 4));
            vm = fmaxf(vm, __shfl_xor(vm, 8));
            float mn = fmaxf(mrow[r], vm);
            alpha[r] = (mn == -INFINITY) ? 0.f : __expf(mrow[r] - mn);
            mrow[r] = mn;
        }
#pragma unroll
        for (int nt = 0; nt < 4; nt++)
#pragma unroll
            for (int r = 0; r < 4; r++)
                sc[nt][r] = (sc[nt][r] == -INFINITY) ? 0.f : __expf(sc[nt][r] - mrow[r]);
#pragma unroll
        for (int r = 0; r < 4; r++) {
            float s = sc[0][r] + sc[1][r] + sc[2][r] + sc[3][r];
            s += __shfl_xor(s, 1);
            s += __shfl_xor(s, 2);
            s += __shfl_xor(s, 4);
            s += __shfl_xor(s, 8);
            lrow[r] = lrow[r] * alpha[r] + s;
#pragma unroll
            for (int nt = 0; nt < 4; nt++) o[nt][r] *= alpha[r];
        }
        // P: C/D layout -> LDS -> A layout
#pragma unroll
        for (int nt = 0; nt < 4; nt++)
#pragma unroll
            for (int r = 0; r < 4; r++)
                Plds[w][quad * 4 + r][nt * 16 + lm] = f2bf(sc[nt][r]);
        __syncthreads();
        short8 pa0 = ld8(&Plds[w][lm][quad * 8]);
        short8 pa1 = ld8(&Plds[w][lm][32 + quad * 8]);
#pragma unroll
        for (int nt = 0; nt < 4; nt++) {
            const unsigned short* vr = Vb + (size_t)(nt * 16 + lm) * S_ + kt * 64 + quad * 8;
            short8 b0 = ld8(vr);
            short8 b1 = ld8(vr + 32);
            o[nt] = __builtin_amdgcn_mfma_f32_16x16x32_bf16(pa0, b0, o[nt], 0, 0, 0);
            o[nt] = __builtin_amdgcn_mfma_f32_16x16x32_bf16(pa1, b1, o[nt], 0, 0, 0);
        }
        __syncthreads();
    }

    int b = bh >> 3, hh = bh & 7;
#pragma unroll
    for (int r = 0; r < 4; r++) {
        float inv = (lrow[r] > 0.f) ? (1.0f / lrow[r]) : 0.f;
        int s = q0 + quad * 4 + r;
#pragma unroll
        for (int nt = 0; nt < 4; nt++)
            ATT[((size_t)b * S_ + s) * D_ + hh * 64 + nt * 16 + lm] = f2bf(o[nt][r] * inv);
    }
}

extern "C" void kernel_launch(void* const* d_in, const int* in_sizes, int n_in,
                              void* d_out, int out_size, void* d_ws, size_t ws_size,
                              hipStream_t stream)
{
    const void* q_in = d_in[0];
    const void* k_in = d_in[1];
    const void* v_in = d_in[2];
    const void* Wq = d_in[3];
    const void* bq = d_in[4];
    const void* Wk = d_in[5];
    const void* bk = d_in[6];
    const void* Wv = d_in[7];
    const void* bv = d_in[8];
    const void* Wo = d_in[9];
    const void* bo = d_in[10];
    unsigned short* ws = (unsigned short*)d_ws;

    int* flag = (int*)d_ws;                      // 32 shorts reserved
    unsigned short* WqT = ws + 32;               // 262144 each
    unsigned short* WkT = WqT + 262144;
    unsigned short* WvT = WkT + 262144;
    unsigned short* WoT = WvT + 262144;
    unsigned short* Qw = WoT + 262144;           // [B,H,S,hd] 4194304
    unsigned short* Kw = Qw + 4194304;           // [B,H,S,hd]
    unsigned short* Vw = Kw + 4194304;           // [B,H,hd,S]  (V transposed)
    unsigned short* Aw = Vw + 4194304;           // [B,S,D] merged-head attn out (bf16)

    detect_dtype<<<1, 256, 0, stream>>>((const unsigned short*)q_in, flag);
    transpose512<<<dim3(8, 8, 4), dim3(64, 4), 0, stream>>>(Wq, Wk, Wv, Wo, WqT, flag);
    gemm512<<<dim3(128, 8), 256, 0, stream>>>(q_in, WqT, bq, Qw, 0, 1, flag);
    gemm512<<<dim3(128, 8), 256, 0, stream>>>(k_in, WkT, bk, Kw, 1, 1, flag);
    gemm512<<<dim3(128, 8), 256, 0, stream>>>(v_in, WvT, bv, Vw, 2, 1, flag);
    attn_kernel<<<dim3(32, 32), 256, 0, stream>>>(Qw, Kw, Vw, Aw);
    gemm512<<<dim3(128, 8), 256, 0, stream>>>(Aw, WoT, bo, d_out, 3, 0, flag);
}

// Round 4
// 364.563 us; speedup vs baseline: 1.5928x; 1.5928x over previous
//
#include <hip/hip_runtime.h>

typedef __attribute__((ext_vector_type(8))) short short8;
typedef __attribute__((ext_vector_type(4))) float f32x4;

#define B_ 4
#define S_ 2048
#define D_ 512
#define H_ 8
#define HD_ 64

__device__ __forceinline__ unsigned short f2bf(float f) {
    unsigned int u = __float_as_uint(f);
    u += 0x7fffu + ((u >> 16) & 1u);
    return (unsigned short)(u >> 16);
}
__device__ __forceinline__ float bf2f(unsigned short h) {
    return __uint_as_float(((unsigned int)h) << 16);
}
__device__ __forceinline__ short8 ld8(const unsigned short* p) {
    return *reinterpret_cast<const short8*>(p);
}

// Dual-dtype 8-element A-row load -> bf16 fragment
__device__ __forceinline__ short8 ldA_dual(const void* X, size_t eoff, int isf32) {
    if (isf32) {
        const float* f = (const float*)X + eoff;
        f32x4 u = *(const f32x4*)f;
        f32x4 v = *(const f32x4*)(f + 4);
        short8 r;
        r[0] = (short)f2bf(u[0]); r[1] = (short)f2bf(u[1]);
        r[2] = (short)f2bf(u[2]); r[3] = (short)f2bf(u[3]);
        r[4] = (short)f2bf(v[0]); r[5] = (short)f2bf(v[1]);
        r[6] = (short)f2bf(v[2]); r[7] = (short)f2bf(v[3]);
        return r;
    }
    return ld8((const unsigned short*)X + eoff);
}

// ---------------- dtype probe: 1 => inputs are f32, 0 => bf16
__global__ void detect_dtype(const unsigned short* __restrict__ q, int* __restrict__ flag) {
    __shared__ int cnt[256];
    int t = threadIdx.x;
    float x = bf2f(q[t]);
    float a = fabsf(x);
    cnt[t] = (a > 1e-5f && a < 1e3f) ? 1 : 0;
    __syncthreads();
    if (t == 0) {
        int s = 0;
        for (int i = 0; i < 256; i++) s += cnt[i];
        *flag = (s < 205) ? 1 : 0;
    }
}

// ---------------- weight transpose: WT[n][k] = W[k][n], 512x512, z = which matrix
__global__ __launch_bounds__(256) void transpose512(
    const void* __restrict__ W0, const void* __restrict__ W1,
    const void* __restrict__ W2, const void* __restrict__ W3,
    unsigned short* __restrict__ outbase, const int* __restrict__ flagp)
{
    __shared__ unsigned short t[64][66];
    int fl = *flagp;
    const void* W = (blockIdx.z == 0) ? W0 : (blockIdx.z == 1) ? W1
                    : (blockIdx.z == 2) ? W2 : W3;
    unsigned short* o = outbase + (size_t)blockIdx.z * 262144;
    int k0 = blockIdx.x * 64, n0 = blockIdx.y * 64;
    int tx = threadIdx.x, ty = threadIdx.y;
#pragma unroll
    for (int r = 0; r < 16; r++) {
        int row = ty * 16 + r;
        size_t idx = (size_t)(k0 + row) * D_ + n0 + tx;
        float v = fl ? ((const float*)W)[idx] : bf2f(((const unsigned short*)W)[idx]);
        t[row][tx] = f2bf(v);
    }
    __syncthreads();
#pragma unroll
    for (int r = 0; r < 16; r++) {
        int row = ty * 16 + r;
        o[(size_t)(n0 + row) * D_ + k0 + tx] = t[tx][row];
    }
}

// ---------------- fused QKV projection: z=0 Q, z=1 K, z=2 V(transposed)
// 128 rows/block, 32 rows/wave. WT blobs contiguous at WTbase + z*262144.
__global__ __launch_bounds__(256) void gemm_qkv(
    const void* __restrict__ Xq, const void* __restrict__ Xk, const void* __restrict__ Xv,
    const unsigned short* __restrict__ WTbase,
    const void* __restrict__ bq, const void* __restrict__ bk, const void* __restrict__ bv,
    unsigned short* __restrict__ Qw, unsigned short* __restrict__ Kw,
    unsigned short* __restrict__ Vw, const int* __restrict__ flagp)
{
    int z = blockIdx.z;
    const void* X = (z == 0) ? Xq : (z == 1) ? Xk : Xv;
    const unsigned short* WT = WTbase + (size_t)z * 262144;
    const void* bias = (z == 0) ? bq : (z == 1) ? bk : bv;
    int fl = *flagp;
    int m0 = blockIdx.x * 128, n0 = blockIdx.y * 64;
    int tid = threadIdx.x;
    int w = tid >> 6, lane = tid & 63, lm = lane & 15, quad = lane >> 4;
    int mbase = m0 + w * 32;

    f32x4 acc[2][4];
#pragma unroll
    for (int mt = 0; mt < 2; mt++)
#pragma unroll
        for (int nt = 0; nt < 4; nt++) acc[mt][nt] = (f32x4){0.f, 0.f, 0.f, 0.f};

    size_t a0 = (size_t)(mbase + lm) * D_ + quad * 8;
    size_t a1 = a0 + (size_t)16 * D_;
    for (int k0 = 0; k0 < D_; k0 += 32) {
        short8 av0 = ldA_dual(X, a0 + k0, fl);
        short8 av1 = ldA_dual(X, a1 + k0, fl);
#pragma unroll
        for (int nt = 0; nt < 4; nt++) {
            short8 bfr = ld8(WT + (size_t)(n0 + nt * 16 + lm) * D_ + k0 + quad * 8);
            acc[0][nt] = __builtin_amdgcn_mfma_f32_16x16x32_bf16(av0, bfr, acc[0][nt], 0, 0, 0);
            acc[1][nt] = __builtin_amdgcn_mfma_f32_16x16x32_bf16(av1, bfr, acc[1][nt], 0, 0, 0);
        }
    }

#pragma unroll
    for (int nt = 0; nt < 4; nt++) {
        int n = n0 + nt * 16 + lm;
        float bv_ = fl ? ((const float*)bias)[n] : bf2f(((const unsigned short*)bias)[n]);
        int hh = n >> 6, d = n & 63;
#pragma unroll
        for (int mt = 0; mt < 2; mt++) {
#pragma unroll
            for (int r = 0; r < 4; r++) {
                int m = mbase + mt * 16 + quad * 4 + r;
                int b = m >> 11, s = m & 2047;
                unsigned short hv = f2bf(acc[mt][nt][r] + bv_);
                if (z == 2)
                    Vw[((size_t)(b * H_ + hh) * HD_ + d) * S_ + s] = hv;    // V^T
                else if (z == 1)
                    Kw[((size_t)(b * H_ + hh) * S_ + s) * HD_ + d] = hv;
                else
                    Qw[((size_t)(b * H_ + hh) * S_ + s) * HD_ + d] = hv;
            }
        }
    }
}

// ---------------- output projection: f32 out, bf16 A
__global__ __launch_bounds__(256) void gemm_out(
    const unsigned short* __restrict__ X, const unsigned short* __restrict__ WT,
    const void* __restrict__ bias, float* __restrict__ out, const int* __restrict__ flagp)
{
    int fl = *flagp;
    int m0 = blockIdx.x * 128, n0 = blockIdx.y * 64;
    int tid = threadIdx.x;
    int w = tid >> 6, lane = tid & 63, lm = lane & 15, quad = lane >> 4;
    int mbase = m0 + w * 32;

    f32x4 acc[2][4];
#pragma unroll
    for (int mt = 0; mt < 2; mt++)
#pragma unroll
        for (int nt = 0; nt < 4; nt++) acc[mt][nt] = (f32x4){0.f, 0.f, 0.f, 0.f};

    const unsigned short* a0 = X + (size_t)(mbase + lm) * D_ + quad * 8;
    const unsigned short* a1 = a0 + (size_t)16 * D_;
    for (int k0 = 0; k0 < D_; k0 += 32) {
        short8 av0 = ld8(a0 + k0);
        short8 av1 = ld8(a1 + k0);
#pragma unroll
        for (int nt = 0; nt < 4; nt++) {
            short8 bfr = ld8(WT + (size_t)(n0 + nt * 16 + lm) * D_ + k0 + quad * 8);
            acc[0][nt] = __builtin_amdgcn_mfma_f32_16x16x32_bf16(av0, bfr, acc[0][nt], 0, 0, 0);
            acc[1][nt] = __builtin_amdgcn_mfma_f32_16x16x32_bf16(av1, bfr, acc[1][nt], 0, 0, 0);
        }
    }

#pragma unroll
    for (int nt = 0; nt < 4; nt++) {
        int n = n0 + nt * 16 + lm;
        float bv_ = fl ? ((const float*)bias)[n] : bf2f(((const unsigned short*)bias)[n]);
#pragma unroll
        for (int mt = 0; mt < 2; mt++)
#pragma unroll
            for (int r = 0; r < 4; r++) {
                int m = mbase + mt * 16 + quad * 4 + r;
                out[(size_t)m * D_ + n] = acc[mt][nt][r] + bv_;
            }
    }
}

// ---------------- flash attention (causal), stripe-paired load balancing.
// Q,K: [B*H, S, hd]; VT: [B*H, hd, S]; ATT: [B, S, H*hd] bf16.
// 128 stripes of 16 q-rows per bh; wave p handles stripes {p, 127-p} => ~33 k-iters/wave.
// No __syncthreads: Plds is per-wave (in-order DS pipeline + waitcnt + parity dbuf).
__global__ __launch_bounds__(256) void attn_kernel(
    const unsigned short* __restrict__ Q, const unsigned short* __restrict__ K,
    const unsigned short* __restrict__ VT, unsigned short* __restrict__ ATT)
{
    __shared__ __align__(16) unsigned short Plds[4][2][16][72];
    int bh = blockIdx.y;
    int tid = threadIdx.x;
    int w = tid >> 6, lane = tid & 63, lm = lane & 15, quad = lane >> 4;
    int p = blockIdx.x * 4 + w;          // pair index 0..63

    const unsigned short* Qb = Q + (size_t)bh * S_ * HD_;
    const unsigned short* Kb = K + (size_t)bh * S_ * HD_;
    const unsigned short* Vb = VT + (size_t)bh * S_ * HD_;
    int b = bh >> 3, hh = bh & 7;

    for (int half = 0; half < 2; half++) {
        int sp = half ? (127 - p) : p;   // stripe index 0..127
        int q0 = sp * 16;
        int ktd = sp >> 2;               // diagonal k-tile

        short8 aq0 = ld8(Qb + (size_t)(q0 + lm) * HD_ + quad * 8);
        short8 aq1 = ld8(Qb + (size_t)(q0 + lm) * HD_ + 32 + quad * 8);

        f32x4 o[4];
#pragma unroll
        for (int nt = 0; nt < 4; nt++) o[nt] = (f32x4){0.f, 0.f, 0.f, 0.f};
        float mrow[4], lrow[4];
#pragma unroll
        for (int r = 0; r < 4; r++) { mrow[r] = -INFINITY; lrow[r] = 0.f; }

        for (int kt = 0; kt <= ktd; kt++) {
            // prefetch K and V fragments together (V doesn't depend on softmax)
            short8 kb0[4], kb1[4], vb0[4], vb1[4];
#pragma unroll
            for (int nt = 0; nt < 4; nt++) {
                const unsigned short* kr = Kb + (size_t)(kt * 64 + nt * 16 + lm) * HD_ + quad * 8;
                kb0[nt] = ld8(kr);
                kb1[nt] = ld8(kr + 32);
                const unsigned short* vr = Vb + (size_t)(nt * 16 + lm) * S_ + kt * 64 + quad * 8;
                vb0[nt] = ld8(vr);
                vb1[nt] = ld8(vr + 32);
            }
            f32x4 sc[4];
#pragma unroll
            for (int nt = 0; nt < 4; nt++) {
                f32x4 z = (f32x4){0.f, 0.f, 0.f, 0.f};
                z = __builtin_amdgcn_mfma_f32_16x16x32_bf16(aq0, kb0[nt], z, 0, 0, 0);
                z = __builtin_amdgcn_mfma_f32_16x16x32_bf16(aq1, kb1[nt], z, 0, 0, 0);
                sc[nt] = z;
            }
            bool diag = (kt == ktd);
#pragma unroll
            for (int nt = 0; nt < 4; nt++) {
#pragma unroll
                for (int r = 0; r < 4; r++) {
                    float v = sc[nt][r] * 0.125f;
                    if (diag) {
                        int key = kt * 64 + nt * 16 + lm;
                        int q = q0 + quad * 4 + r;
                        if (key > q) v = -INFINITY;
                    }
                    sc[nt][r] = v;
                }
            }
            float alpha[4];
#pragma unroll
            for (int r = 0; r < 4; r++) {
                float vm = fmaxf(fmaxf(sc[0][r], sc[1][r]), fmaxf(sc[2][r], sc[3][r]));
                vm = fmaxf(vm, __shfl_xor(vm, 1));
                vm = fmaxf(vm, __shfl_xor(vm, 2));
                vm = fmaxf(vm, __shfl_xor(vm, 4));
                vm = fmaxf(vm, __shfl_xor(vm, 8));
                float mn = fmaxf(mrow[r], vm);
                alpha[r] = (mn == -INFINITY) ? 0.f : __expf(mrow[r] - mn);
                mrow[r] = mn;
            }
#pragma unroll
            for (int nt = 0; nt < 4; nt++)
#pragma unroll
                for (int r = 0; r < 4; r++)
                    sc[nt][r] = (sc[nt][r] == -INFINITY) ? 0.f : __expf(sc[nt][r] - mrow[r]);
#pragma unroll
            for (int r = 0; r < 4; r++) {
                float s = sc[0][r] + sc[1][r] + sc[2][r] + sc[3][r];
                s += __shfl_xor(s, 1);
                s += __shfl_xor(s, 2);
                s += __shfl_xor(s, 4);
                s += __shfl_xor(s, 8);
                lrow[r] = lrow[r] * alpha[r] + s;
#pragma unroll
                for (int nt = 0; nt < 4; nt++) o[nt][r] *= alpha[r];
            }
            // P: C/D layout -> per-wave LDS (kt-parity buffer) -> A layout
            unsigned short (*Pb)[72] = Plds[w][kt & 1];
#pragma unroll
            for (int nt = 0; nt < 4; nt++)
#pragma unroll
                for (int r = 0; r < 4; r++)
                    Pb[quad * 4 + r][nt * 16 + lm] = f2bf(sc[nt][r]);
            asm volatile("s_waitcnt lgkmcnt(0)" ::: "memory");
            __builtin_amdgcn_wave_barrier();
            short8 pa0 = ld8(&Pb[lm][quad * 8]);
            short8 pa1 = ld8(&Pb[lm][32 + quad * 8]);
#pragma unroll
            for (int nt = 0; nt < 4; nt++) {
                o[nt] = __builtin_amdgcn_mfma_f32_16x16x32_bf16(pa0, vb0[nt], o[nt], 0, 0, 0);
                o[nt] = __builtin_amdgcn_mfma_f32_16x16x32_bf16(pa1, vb1[nt], o[nt], 0, 0, 0);
            }
        }

#pragma unroll
        for (int r = 0; r < 4; r++) {
            float inv = (lrow[r] > 0.f) ? (1.0f / lrow[r]) : 0.f;
            int s = q0 + quad * 4 + r;
#pragma unroll
            for (int nt = 0; nt < 4; nt++)
                ATT[((size_t)b * S_ + s) * D_ + hh * 64 + nt * 16 + lm] = f2bf(o[nt][r] * inv);
        }
    }
}

extern "C" void kernel_launch(void* const* d_in, const int* in_sizes, int n_in,
                              void* d_out, int out_size, void* d_ws, size_t ws_size,
                              hipStream_t stream)
{
    const void* q_in = d_in[0];
    const void* k_in = d_in[1];
    const void* v_in = d_in[2];
    const void* Wq = d_in[3];
    const void* bq = d_in[4];
    const void* Wk = d_in[5];
    const void* bk = d_in[6];
    const void* Wv = d_in[7];
    const void* bv = d_in[8];
    const void* Wo = d_in[9];
    const void* bo = d_in[10];
    unsigned short* ws = (unsigned short*)d_ws;

    int* flag = (int*)d_ws;                      // 32 shorts reserved
    unsigned short* WqT = ws + 32;               // WqT,WkT,WvT contiguous (gemm_qkv indexes by z)
    unsigned short* WkT = WqT + 262144;
    unsigned short* WvT = WkT + 262144;
    unsigned short* WoT = WvT + 262144;
    unsigned short* Qw = WoT + 262144;           // [B,H,S,hd]
    unsigned short* Kw = Qw + 4194304;           // [B,H,S,hd]
    unsigned short* Vw = Kw + 4194304;           // [B,H,hd,S]  (V transposed)
    unsigned short* Aw = Vw + 4194304;           // [B,S,D] merged-head attn out (bf16)

    detect_dtype<<<1, 256, 0, stream>>>((const unsigned short*)q_in, flag);
    transpose512<<<dim3(8, 8, 4), dim3(64, 4), 0, stream>>>(Wq, Wk, Wv, Wo, WqT, flag);
    gemm_qkv<<<dim3(64, 8, 3), 256, 0, stream>>>(q_in, k_in, v_in, WqT, bq, bk, bv,
                                                 Qw, Kw, Vw, flag);
    attn_kernel<<<dim3(16, 32), 256, 0, stream>>>(Qw, Kw, Vw, Aw);
    gemm_out<<<dim3(64, 8), 256, 0, stream>>>(Aw, WoT, bo, (float*)d_out, flag);
}

// Round 6
// 277.333 us; speedup vs baseline: 2.0938x; 1.3145x over previous
//
#include <hip/hip_runtime.h>

typedef __attribute__((ext_vector_type(8))) short short8;
typedef __attribute__((ext_vector_type(4))) float f32x4;
typedef __attribute__((ext_vector_type(4))) unsigned short us4;

#define B_ 4
#define S_ 2048
#define D_ 512
#define H_ 8
#define HD_ 64

__device__ __forceinline__ unsigned short f2bf(float f) {
    unsigned int u = __float_as_uint(f);
    u += 0x7fffu + ((u >> 16) & 1u);
    return (unsigned short)(u >> 16);
}
__device__ __forceinline__ float bf2f(unsigned short h) {
    return __uint_as_float(((unsigned int)h) << 16);
}
__device__ __forceinline__ short8 ld8(const unsigned short* p) {
    return *reinterpret_cast<const short8*>(p);
}
// async 16B/lane global->LDS: lane's data lands at ldsbase + lane*16
__device__ __forceinline__ void async16(const unsigned short* g, unsigned short* l) {
    __builtin_amdgcn_global_load_lds(
        (const __attribute__((address_space(1))) void*)(const void*)g,
        (__attribute__((address_space(3))) void*)(void*)l, 16, 0, 0);
}

// ---------------- dtype probe: 1 => inputs are f32, 0 => bf16
__global__ void detect_dtype(const unsigned short* __restrict__ q, int* __restrict__ flag) {
    __shared__ int cnt[256];
    int t = threadIdx.x;
    float x = bf2f(q[t]);
    float a = fabsf(x);
    cnt[t] = (a > 1e-5f && a < 1e3f) ? 1 : 0;
    __syncthreads();
    if (t == 0) {
        int s = 0;
        for (int i = 0; i < 256; i++) s += cnt[i];
        *flag = (s < 205) ? 1 : 0;
    }
}

// ---------------- convert q/k/v activations to bf16 (or copy if already bf16)
__global__ __launch_bounds__(256) void cvt_bf16(
    const void* __restrict__ q, const void* __restrict__ k, const void* __restrict__ v,
    unsigned short* __restrict__ out, const int* __restrict__ flagp)
{
    int fl = *flagp;
    int z = blockIdx.z;
    const void* X = (z == 0) ? q : (z == 1) ? k : v;
    unsigned short* o = out + (size_t)z * 4194304;
    size_t i = ((size_t)blockIdx.x * 256 + threadIdx.x) * 4;
    if (fl) {
        f32x4 u = *(const f32x4*)((const float*)X + i);
        us4 r;
        r.x = f2bf(u[0]); r.y = f2bf(u[1]); r.z = f2bf(u[2]); r.w = f2bf(u[3]);
        *(us4*)(o + i) = r;
    } else {
        *(us4*)(o + i) = *(const us4*)((const unsigned short*)X + i);
    }
}

// ---------------- weight transpose: WT[n][k] = W[k][n], 512x512, z = which matrix
__global__ __launch_bounds__(256) void transpose512(
    const void* __restrict__ W0, const void* __restrict__ W1,
    const void* __restrict__ W2, const void* __restrict__ W3,
    unsigned short* __restrict__ outbase, const int* __restrict__ flagp)
{
    __shared__ unsigned short t[64][66];
    int fl = *flagp;
    const void* W = (blockIdx.z == 0) ? W0 : (blockIdx.z == 1) ? W1
                    : (blockIdx.z == 2) ? W2 : W3;
    unsigned short* o = outbase + (size_t)blockIdx.z * 262144;
    int k0 = blockIdx.x * 64, n0 = blockIdx.y * 64;
    int tx = threadIdx.x, ty = threadIdx.y;
#pragma unroll
    for (int r = 0; r < 16; r++) {
        int row = ty * 16 + r;
        size_t idx = (size_t)(k0 + row) * D_ + n0 + tx;
        float v = fl ? ((const float*)W)[idx] : bf2f(((const unsigned short*)W)[idx]);
        t[row][tx] = f2bf(v);
    }
    __syncthreads();
#pragma unroll
    for (int r = 0; r < 16; r++) {
        int row = ty * 16 + r;
        o[(size_t)(n0 + row) * D_ + k0 + tx] = t[tx][row];
    }
}

// ---------------- m97-style tiled GEMM body: 128x128 tile, BK=32, 4 waves,
// global_load_lds staging + XOR k-chunk swizzle. A[M,512] bf16, B=WT[N,K] bf16.
// Produces acc[4][4] (f32x4 each) for wave tile (w&1)*64 m, (w>>1)*64 n.
#define GEMM_BODY(Xp, WTp)                                                              \
    int tid = threadIdx.x;                                                              \
    int w = tid >> 6, lane = tid & 63, lm = lane & 15, quad = lane >> 4;                \
    int wm = (w & 1) * 64, wn = (w >> 1) * 64;                                          \
    int srow = w * 32 + (lane >> 2);                                                    \
    int clog = (lane & 3) ^ ((lane >> 3) & 3);   /* logical k-chunk lane fetches */     \
    int csw = quad ^ ((lm >> 1) & 3);            /* physical chunk for frag reads */    \
    const unsigned short* gA = (Xp) + (size_t)(m0 + srow) * D_ + clog * 8;              \
    const unsigned short* gB = (WTp) + (size_t)(n0 + srow) * D_ + clog * 8;             \
    unsigned short* lA = &Atile[(w * 32) * 32];                                         \
    unsigned short* lB = &Btile[(w * 32) * 32];                                         \
    f32x4 acc[4][4];                                                                    \
    _Pragma("unroll") for (int mt = 0; mt < 4; mt++)                                    \
        _Pragma("unroll") for (int nt = 0; nt < 4; nt++)                                \
            acc[mt][nt] = (f32x4){0.f, 0.f, 0.f, 0.f};                                  \
    for (int k0 = 0; k0 < D_; k0 += 32) {                                               \
        async16(gA + k0, lA);                                                           \
        async16(gA + k0 + (size_t)16 * D_, lA + 16 * 32);                               \
        async16(gB + k0, lB);                                                           \
        async16(gB + k0 + (size_t)16 * D_, lB + 16 * 32);                               \
        asm volatile("s_waitcnt vmcnt(0)" ::: "memory");                                \
        __syncthreads();                                                                \
        short8 af[4], bfr[4];                                                           \
        _Pragma("unroll") for (int mt = 0; mt < 4; mt++)                                \
            af[mt] = ld8(&Atile[(wm + mt * 16 + lm) * 32 + csw * 8]);                   \
        _Pragma("unroll") for (int nt = 0; nt < 4; nt++)                                \
            bfr[nt] = ld8(&Btile[(wn + nt * 16 + lm) * 32 + csw * 8]);                  \
        _Pragma("unroll") for (int mt = 0; mt < 4; mt++)                                \
            _Pragma("unroll") for (int nt = 0; nt < 4; nt++)                            \
                acc[mt][nt] = __builtin_amdgcn_mfma_f32_16x16x32_bf16(                  \
                    af[mt], bfr[nt], acc[mt][nt], 0, 0, 0);                             \
        __syncthreads();                                                                \
    }

// ---------------- fused QKV projection: z=0 Q, z=1 K, z=2 V(transposed)
__global__ __launch_bounds__(256) void gemm_qkv(
    const unsigned short* __restrict__ Xbf, const unsigned short* __restrict__ WTbase,
    const void* __restrict__ bq, const void* __restrict__ bk, const void* __restrict__ bv,
    unsigned short* __restrict__ Qw, unsigned short* __restrict__ Kw,
    unsigned short* __restrict__ Vw, const int* __restrict__ flagp)
{
    __shared__ __align__(16) unsigned short Atile[128 * 32];
    __shared__ __align__(16) unsigned short Btile[128 * 32];
    int z = blockIdx.z;
    const unsigned short* X = Xbf + (size_t)z * 4194304;
    const void* bias = (z == 0) ? bq : (z == 1) ? bk : bv;
    int fl = *flagp;
    int m0 = blockIdx.x * 128, n0 = blockIdx.y * 128;

    GEMM_BODY(X, WTbase + (size_t)z * 262144)

#pragma unroll
    for (int nt = 0; nt < 4; nt++) {
        int n = n0 + wn + nt * 16 + lm;
        float bv_ = fl ? ((const float*)bias)[n] : bf2f(((const unsigned short*)bias)[n]);
        int hh = n >> 6, d = n & 63;
#pragma unroll
        for (int mt = 0; mt < 4; mt++) {
#pragma unroll
            for (int r = 0; r < 4; r++) {
                int m = m0 + wm + mt * 16 + quad * 4 + r;
                int b = m >> 11, s = m & 2047;
                unsigned short hv = f2bf(acc[mt][nt][r] + bv_);
                if (z == 2)
                    Vw[((size_t)(b * H_ + hh) * HD_ + d) * S_ + s] = hv;    // V^T
                else if (z == 1)
                    Kw[((size_t)(b * H_ + hh) * S_ + s) * HD_ + d] = hv;
                else
                    Qw[((size_t)(b * H_ + hh) * S_ + s) * HD_ + d] = hv;
            }
        }
    }
}

// ---------------- output projection: f32 out
__global__ __launch_bounds__(256) void gemm_out(
    const unsigned short* __restrict__ Xa, const unsigned short* __restrict__ WT,
    const void* __restrict__ bias, float* __restrict__ out, const int* __restrict__ flagp)
{
    __shared__ __align__(16) unsigned short Atile[128 * 32];
    __shared__ __align__(16) unsigned short Btile[128 * 32];
    int fl = *flagp;
    int m0 = blockIdx.x * 128, n0 = blockIdx.y * 128;

    GEMM_BODY(Xa, WT)

#pragma unroll
    for (int nt = 0; nt < 4; nt++) {
        int n = n0 + wn + nt * 16 + lm;
        float bv_ = fl ? ((const float*)bias)[n] : bf2f(((const unsigned short*)bias)[n]);
#pragma unroll
        for (int mt = 0; mt < 4; mt++)
#pragma unroll
            for (int r = 0; r < 4; r++) {
                int m = m0 + wm + mt * 16 + quad * 4 + r;
                out[(size_t)m * D_ + n] = acc[mt][nt][r] + bv_;
            }
    }
}

// ---------------- flash attention (causal), stripe-paired load balancing.
__global__ __launch_bounds__(256) void attn_kernel(
    const unsigned short* __restrict__ Q, const unsigned short* __restrict__ K,
    const unsigned short* __restrict__ VT, unsigned short* __restrict__ ATT)
{
    __shared__ __align__(16) unsigned short Plds[4][2][16][72];
    int bh = blockIdx.y;
    int tid = threadIdx.x;
    int w = tid >> 6, lane = tid & 63, lm = lane & 15, quad = lane >> 4;
    int p = blockIdx.x * 4 + w;          // pair index 0..63

    const unsigned short* Qb = Q + (size_t)bh * S_ * HD_;
    const unsigned short* Kb = K + (size_t)bh * S_ * HD_;
    const unsigned short* Vb = VT + (size_t)bh * S_ * HD_;
    int b = bh >> 3, hh = bh & 7;

    for (int half = 0; half < 2; half++) {
        int sp = half ? (127 - p) : p;   // stripe index 0..127
        int q0 = sp * 16;
        int ktd = sp >> 2;               // diagonal k-tile

        short8 aq0 = ld8(Qb + (size_t)(q0 + lm) * HD_ + quad * 8);
        short8 aq1 = ld8(Qb + (size_t)(q0 + lm) * HD_ + 32 + quad * 8);

        f32x4 o[4];
#pragma unroll
        for (int nt = 0; nt < 4; nt++) o[nt] = (f32x4){0.f, 0.f, 0.f, 0.f};
        float mrow[4], lrow[4];
#pragma unroll
        for (int r = 0; r < 4; r++) { mrow[r] = -INFINITY; lrow[r] = 0.f; }

        for (int kt = 0; kt <= ktd; kt++) {
            short8 kb0[4], kb1[4], vb0[4], vb1[4];
#pragma unroll
            for (int nt = 0; nt < 4; nt++) {
                const unsigned short* kr = Kb + (size_t)(kt * 64 + nt * 16 + lm) * HD_ + quad * 8;
                kb0[nt] = ld8(kr);
                kb1[nt] = ld8(kr + 32);
                const unsigned short* vr = Vb + (size_t)(nt * 16 + lm) * S_ + kt * 64 + quad * 8;
                vb0[nt] = ld8(vr);
                vb1[nt] = ld8(vr + 32);
            }
            f32x4 sc[4];
#pragma unroll
            for (int nt = 0; nt < 4; nt++) {
                f32x4 z = (f32x4){0.f, 0.f, 0.f, 0.f};
                z = __builtin_amdgcn_mfma_f32_16x16x32_bf16(aq0, kb0[nt], z, 0, 0, 0);
                z = __builtin_amdgcn_mfma_f32_16x16x32_bf16(aq1, kb1[nt], z, 0, 0, 0);
                sc[nt] = z;
            }
            bool diag = (kt == ktd);
#pragma unroll
            for (int nt = 0; nt < 4; nt++) {
#pragma unroll
                for (int r = 0; r < 4; r++) {
                    float v = sc[nt][r] * 0.125f;
                    if (diag) {
                        int key = kt * 64 + nt * 16 + lm;
                        int q = q0 + quad * 4 + r;
                        if (key > q) v = -INFINITY;
                    }
                    sc[nt][r] = v;
                }
            }
            float alpha[4];
#pragma unroll
            for (int r = 0; r < 4; r++) {
                float vm = fmaxf(fmaxf(sc[0][r], sc[1][r]), fmaxf(sc[2][r], sc[3][r]));
                vm = fmaxf(vm, __shfl_xor(vm, 1));
                vm = fmaxf(vm, __shfl_xor(vm, 2));
                vm = fmaxf(vm, __shfl_xor(vm, 4));
                vm = fmaxf(vm, __shfl_xor(vm, 8));
                float mn = fmaxf(mrow[r], vm);
                alpha[r] = (mn == -INFINITY) ? 0.f : __expf(mrow[r] - mn);
                mrow[r] = mn;
            }
#pragma unroll
            for (int nt = 0; nt < 4; nt++)
#pragma unroll
                for (int r = 0; r < 4; r++)
                    sc[nt][r] = (sc[nt][r] == -INFINITY) ? 0.f : __expf(sc[nt][r] - mrow[r]);
#pragma unroll
            for (int r = 0; r < 4; r++) {
                float s = sc[0][r] + sc[1][r] + sc[2][r] + sc[3][r];
                s += __shfl_xor(s, 1);
                s += __shfl_xor(s, 2);
                s += __shfl_xor(s, 4);
                s += __shfl_xor(s, 8);
                lrow[r] = lrow[r] * alpha[r] + s;
#pragma unroll
                for (int nt = 0; nt < 4; nt++) o[nt][r] *= alpha[r];
            }
            unsigned short (*Pb)[72] = Plds[w][kt & 1];
#pragma unroll
            for (int nt = 0; nt < 4; nt++)
#pragma unroll
                for (int r = 0; r < 4; r++)
                    Pb[quad * 4 + r][nt * 16 + lm] = f2bf(sc[nt][r]);
            asm volatile("s_waitcnt lgkmcnt(0)" ::: "memory");
            __builtin_amdgcn_wave_barrier();
            short8 pa0 = ld8(&Pb[lm][quad * 8]);
            short8 pa1 = ld8(&Pb[lm][32 + quad * 8]);
#pragma unroll
            for (int nt = 0; nt < 4; nt++) {
                o[nt] = __builtin_amdgcn_mfma_f32_16x16x32_bf16(pa0, vb0[nt], o[nt], 0, 0, 0);
                o[nt] = __builtin_amdgcn_mfma_f32_16x16x32_bf16(pa1, vb1[nt], o[nt], 0, 0, 0);
            }
        }

#pragma unroll
        for (int r = 0; r < 4; r++) {
            float inv = (lrow[r] > 0.f) ? (1.0f / lrow[r]) : 0.f;
            int s = q0 + quad * 4 + r;
#pragma unroll
            for (int nt = 0; nt < 4; nt++)
                ATT[((size_t)b * S_ + s) * D_ + hh * 64 + nt * 16 + lm] = f2bf(o[nt][r] * inv);
        }
    }
}

extern "C" void kernel_launch(void* const* d_in, const int* in_sizes, int n_in,
                              void* d_out, int out_size, void* d_ws, size_t ws_size,
                              hipStream_t stream)
{
    const void* q_in = d_in[0];
    const void* k_in = d_in[1];
    const void* v_in = d_in[2];
    const void* Wq = d_in[3];
    const void* bq = d_in[4];
    const void* Wk = d_in[5];
    const void* bk = d_in[6];
    const void* Wv = d_in[7];
    const void* bv = d_in[8];
    const void* Wo = d_in[9];
    const void* bo = d_in[10];
    unsigned short* ws = (unsigned short*)d_ws;

    int* flag = (int*)d_ws;                      // 32 shorts reserved
    unsigned short* WqT = ws + 32;               // WqT,WkT,WvT contiguous
    unsigned short* WkT = WqT + 262144;
    unsigned short* WvT = WkT + 262144;
    unsigned short* WoT = WvT + 262144;
    unsigned short* Xbf = WoT + 262144;          // [3][8192][512] bf16 activations
    unsigned short* Qw = Xbf + 12582912;         // [B,H,S,hd]
    unsigned short* Kw = Qw + 4194304;           // [B,H,S,hd]
    unsigned short* Vw = Kw + 4194304;           // [B,H,hd,S]  (V transposed)
    unsigned short* Aw = Vw + 4194304;           // [B,S,D] merged-head attn out (bf16)

    detect_dtype<<<1, 256, 0, stream>>>((const unsigned short*)q_in, flag);
    transpose512<<<dim3(8, 8, 4), dim3(64, 4), 0, stream>>>(Wq, Wk, Wv, Wo, WqT, flag);
    cvt_bf16<<<dim3(4096, 1, 3), 256, 0, stream>>>(q_in, k_in, v_in, Xbf, flag);
    gemm_qkv<<<dim3(64, 4, 3), 256, 0, stream>>>(Xbf, WqT, bq, bk, bv, Qw, Kw, Vw, flag);
    attn_kernel<<<dim3(16, 32), 256, 0, stream>>>(Qw, Kw, Vw, Aw);
    gemm_out<<<dim3(64, 4), 256, 0, stream>>>(Aw, WoT, bo, (float*)d_out, flag);
}